// Round 1
// baseline (596.592 us; speedup 1.0000x reference)
//
#include <hip/hip_runtime.h>
#include <math.h>

#define NN 102400
#define FD 128
#define KC 16
#define BG 64
#define NPG 1600
#define NE 3276800
#define HB 1024          // edge-pass blocks
#define EH (NE / HB)     // 3200 edges per block
// zero region: adj_raw(16384) cc_raw(16384) outx(131072) scal(8) done(8) deg(102400) gtot(64)
#define ZTOT (16384 + 16384 + 131072 + 8 + 8 + 102400 + 64)

__device__ __forceinline__ void glob_addf(float* p, float v) {
  unsafeAtomicAdd(p, v);
}
__device__ __forceinline__ unsigned f2bf(float f) {
  unsigned u = __float_as_uint(f);
  u += 0x7FFFu + ((u >> 16) & 1u);
  return (u >> 16) & 0xFFFFu;
}
__device__ __forceinline__ float bf2f(unsigned h) {
  return __uint_as_float(h << 16);
}

// -------------------- k_s: softmax^2(x@W+b) + zero accumulators --------------------
__global__ __launch_bounds__(256) void k_s(const float* __restrict__ x,
    const float* __restrict__ W, const float* __restrict__ bb,
    float* __restrict__ s, unsigned* __restrict__ zbase) {
  const int t = threadIdx.x;
  const int n = blockIdx.x * 256 + t;
  for (int i = n; i < ZTOT; i += NN) zbase[i] = 0u;
  float acc[KC];
#pragma unroll
  for (int k = 0; k < KC; ++k) acc[k] = bb[k];
  const float4* xr = (const float4*)(x + (size_t)n * FD);
#pragma unroll 4
  for (int c = 0; c < FD / 4; ++c) {
    float4 v = xr[c];
    const float* wr = W + c * 4 * KC;   // wave-uniform -> scalar loads
#pragma unroll
    for (int k = 0; k < KC; ++k)
      acc[k] += v.x * wr[k] + v.y * wr[KC + k] + v.z * wr[2 * KC + k] + v.w * wr[3 * KC + k];
  }
#pragma unroll
  for (int r = 0; r < 2; ++r) {
    float m = acc[0];
#pragma unroll
    for (int k = 1; k < KC; ++k) m = fmaxf(m, acc[k]);
    float sum = 0.f;
#pragma unroll
    for (int k = 0; k < KC; ++k) { acc[k] = expf(acc[k] - m); sum += acc[k]; }
    float inv = 1.f / sum;
#pragma unroll
    for (int k = 0; k < KC; ++k) acc[k] *= inv;
  }
  float4* so = (float4*)(s + (size_t)n * KC);
  so[0] = make_float4(acc[0], acc[1], acc[2], acc[3]);
  so[1] = make_float4(acc[4], acc[5], acc[6], acc[7]);
  so[2] = make_float4(acc[8], acc[9], acc[10], acc[11]);
  so[3] = make_float4(acc[12], acc[13], acc[14], acc[15]);
}

// -------------------- k_hist: global per-src histogram + per-graph totals ----------
__global__ __launch_bounds__(256) void k_hist(const int* __restrict__ esrc,
    unsigned* __restrict__ deg, unsigned* __restrict__ gtot) {
  __shared__ unsigned h[BG];
  const int t = threadIdx.x, b = blockIdx.x;
  if (t < BG) h[t] = 0u;
  __syncthreads();
  const int e0 = b * EH;
  for (int i = t; i < EH; i += 256) {
    int s0 = esrc[e0 + i];
    atomicAdd(&deg[s0], 1u);                       // fire-and-forget
    atomicAdd(&h[(unsigned)s0 / (unsigned)NPG], 1u);
  }
  __syncthreads();
  if (t < BG && h[t]) atomicAdd(&gtot[t], h[t]);
}

// -------------------- k_scan_b: 64-entry serial scan -> gbase ----------------------
__global__ void k_scan_b(const unsigned* __restrict__ gtot, unsigned* __restrict__ gbase) {
  if (threadIdx.x == 0) {
    unsigned run = 0;
    for (int g = 0; g < BG; ++g) { gbase[g] = run; run += gtot[g]; }
    gbase[BG] = run;   // == NE
  }
}

// -------------- k_scan_g: per-graph exclusive scan of deg -> atomic cursors --------
// In-place: deg[n] becomes the global start offset (cursor) of row n.
__global__ __launch_bounds__(64) void k_scan_g(unsigned* __restrict__ deg,
    const unsigned* __restrict__ gbase) {
  const int t = threadIdx.x, g = blockIdx.x;
  unsigned* dg = deg + (size_t)g * NPG;
  unsigned loc[25];
  unsigned run = 0;
#pragma unroll
  for (int i = 0; i < 25; ++i) { loc[i] = run; run += dg[t * 25 + i]; }
  unsigned inc = run;
#pragma unroll
  for (int o = 1; o < 64; o <<= 1) {
    unsigned nb = __shfl_up(inc, o, 64);
    if (t >= o) inc += nb;
  }
  const unsigned excl = (inc - run) + gbase[g];
#pragma unroll
  for (int i = 0; i < 25; ++i) dg[t * 25 + i] = excl + loc[i];
}

// -------------------- k_scatter: counting-sort payload directly by src -------------
__global__ __launch_bounds__(256) void k_scatter(const float* __restrict__ ew,
    const int* __restrict__ esrc, const int* __restrict__ edst,
    unsigned* __restrict__ cur, unsigned* __restrict__ pay) {
  const int t = threadIdx.x, b = blockIdx.x;
  const int e0 = b * EH;
  for (int i = t; i < EH; i += 256) {
    int e = e0 + i;
    int s0 = esrc[e], d0 = edst[e];
    float w = ew[e];
    unsigned g = (unsigned)s0 / (unsigned)NPG;
    unsigned pos = atomicAdd(&cur[s0], 1u);        // returns old -> unique slot
    pay[pos] = (((unsigned)d0 - g * NPG) << 16) | f2bf(w);
  }
}

// -------------------- k_adj: single-gather inner loop; den folded ------------------
// After k_scatter, cur[n] == global END pointer of row n (start = cur[n-1] or gbase[g]).
__global__ __launch_bounds__(256, 6) void k_adj(const float* __restrict__ s,
    const unsigned* __restrict__ pay, const unsigned* __restrict__ gbase,
    const unsigned* __restrict__ rend,
    float* __restrict__ adj_raw, float* __restrict__ den) {
  __shared__ float red[16 * 256];
  __shared__ float scr[4];
  const int t = threadIdx.x;
  const int g = blockIdx.x & 63;            // XCD-spread graphs
  const int oct = blockIdx.x >> 6;          // 0..31
  const int l = t & 15;
  const int slice = oct * 16 + (t >> 4);    // 0..511 per graph
  const int sw = (t >> 4) & 3;              // slice-in-wave
  const unsigned gb = gbase[g];
  const unsigned* re = rend + (size_t)g * NPG;
  const float* sG = s + (size_t)g * NPG * KC;
  float acc[16];
#pragma unroll
  for (int k = 0; k < 16; ++k) acc[k] = 0.f;
  float dacc = 0.f;
  for (int i = slice; i < NPG; i += 512) {
    const unsigned e0 = (i == 0) ? gb : re[i - 1];
    const unsigned e1 = re[i];
    float m = 0.f;
    unsigned e = e0;
    for (; e + 4 <= e1; e += 4) {           // sequential payload, 4 gathers in flight
      unsigned pk0 = pay[e], pk1 = pay[e + 1], pk2 = pay[e + 2], pk3 = pay[e + 3];
      float sv0 = sG[(pk0 >> 16) * KC + l];
      float sv1 = sG[(pk1 >> 16) * KC + l];
      float sv2 = sG[(pk2 >> 16) * KC + l];
      float sv3 = sG[(pk3 >> 16) * KC + l];
      float t0 = bf2f(pk0 & 0xFFFFu) * sv0;
      float t1 = bf2f(pk1 & 0xFFFFu) * sv1;
      float t2 = bf2f(pk2 & 0xFFFFu) * sv2;
      float t3 = bf2f(pk3 & 0xFFFFu) * sv3;
      m += (t0 + t1) + (t2 + t3);
      dacc = fmaf(t0, sv0, dacc);
      dacc = fmaf(t1, sv1, dacc);
      dacc = fmaf(t2, sv2, dacc);
      dacc = fmaf(t3, sv3, dacc);
    }
    for (; e < e1; ++e) {
      unsigned pk0 = pay[e];
      float sv0 = sG[(pk0 >> 16) * KC + l];
      float t0 = bf2f(pk0 & 0xFFFFu) * sv0;
      m += t0;
      dacc = fmaf(t0, sv0, dacc);
    }
    const float si = sG[i * KC + l];
#pragma unroll
    for (int k = 0; k < 16; ++k)
      acc[k] = fmaf(__shfl(si, sw * 16 + k, 64), m, acc[k]);
  }
  const int sb = t >> 4;
#pragma unroll
  for (int k = 0; k < 16; ++k) red[sb * 256 + k * 16 + l] = acc[k];
  __syncthreads();
  float sum = 0.f;
#pragma unroll
  for (int sl = 0; sl < 16; ++sl) sum += red[sl * 256 + t];
  glob_addf(adj_raw + g * 256 + t, sum);
#pragma unroll
  for (int o = 32; o > 0; o >>= 1) dacc += __shfl_down(dacc, o, 64);
  __syncthreads();
  if ((t & 63) == 0) scr[t >> 6] = dacc;
  __syncthreads();
  if (t == 0) glob_addf(den, scr[0] + scr[1] + scr[2] + scr[3]);
}

// -------------------- k_mid: CC = S^T S, out_x = S^T X -----------------------------
__global__ __launch_bounds__(256, 8) void k_mid(const float* __restrict__ s,
    const float* __restrict__ x, float* __restrict__ cc_raw,
    float* __restrict__ outx_raw) {
  __shared__ float st[100 * KC];
  const int t = threadIdx.x;
  const int g = blockIdx.x >> 4, sub = blockIdx.x & 15;
  const int n0 = g * NPG + sub * 100;
  const int j = t & 127, h = t >> 7;
  const int kc = t >> 4, lc = t & 15;
  for (int u = t; u < 100 * KC; u += 256) st[u] = s[(size_t)n0 * KC + u];
  __syncthreads();
  float accX[8] = {0.f, 0.f, 0.f, 0.f, 0.f, 0.f, 0.f, 0.f};
  float accC = 0.f;
  for (int i = 0; i < 100; ++i) {
    const float xv = x[(size_t)(n0 + i) * FD + j];
    const float* si = st + i * KC;
#pragma unroll
    for (int kk = 0; kk < 8; ++kk) accX[kk] = fmaf(si[h * 8 + kk], xv, accX[kk]);
    accC = fmaf(si[kc], si[lc], accC);
  }
#pragma unroll
  for (int kk = 0; kk < 8; ++kk)
    glob_addf(outx_raw + g * 2048 + (h * 8 + kk) * 128 + j, accX[kk]);
  glob_addf(cc_raw + g * 256 + t, accC);
}

// -------------------- k_post: normalize adj, trace, ortho, SELU --------------------
__device__ __forceinline__ float bred(float v, float* scr) {
#pragma unroll
  for (int o = 32; o > 0; o >>= 1) v += __shfl_down(v, o, 64);
  __syncthreads();
  if ((threadIdx.x & 63) == 0) scr[threadIdx.x >> 6] = v;
  __syncthreads();
  return scr[0] + scr[1] + scr[2] + scr[3];
}

__global__ __launch_bounds__(256) void k_post(const float* __restrict__ adj_raw,
    const float* __restrict__ cc_raw, const float* __restrict__ outx_raw,
    float* __restrict__ out, float* __restrict__ scal, unsigned* __restrict__ done) {
  const int b = blockIdx.x, t = threadIdx.x;
  const int k = t >> 4, l = t & 15;
  __shared__ float m[16 * 17];
  __shared__ float dk[16];
  __shared__ float scr[4];
  const float raw = adj_raw[b * 256 + t];
  const float masked = (k == l) ? 0.f : raw;
  m[k * 17 + l] = masked;
  __syncthreads();
  if (t < 16) {
    float rs = 0.f;
#pragma unroll
    for (int ll = 0; ll < 16; ++ll) rs += m[t * 17 + ll];
    dk[t] = sqrtf(rs) + 1e-12f;
  }
  __syncthreads();
  out[131072 + b * 256 + t] = masked / (dk[k] * dk[l]);
  float tr = bred((k == l) ? raw : 0.f, scr);
  if (t == 0) glob_addf(scal + 1, tr);
  const float c = cc_raw[b * 256 + t];
  float n2 = bred(c * c, scr);
  float diff = c / sqrtf(n2) - ((k == l) ? 0.25f : 0.f);
  float d2 = bred(diff * diff, scr);
  if (t == 0) glob_addf(scal + 2, sqrtf(d2));
  for (int idx = b * 256 + t; idx < 131072; idx += 16384) {
    float xv = outx_raw[idx];
    out[idx] = xv > 0.f ? 1.0507009873554805f * xv
                        : 1.0507009873554805f * 1.6732632423543772f * expm1f(xv);
  }
  __syncthreads();
  if (t == 0) {
    __threadfence();
    unsigned v = __hip_atomic_fetch_add(done, 1u, __ATOMIC_ACQ_REL,
                                        __HIP_MEMORY_SCOPE_AGENT);
    if (v == 63u) {   // last block: all contributions visible
      float den   = __hip_atomic_load(scal + 0, __ATOMIC_RELAXED, __HIP_MEMORY_SCOPE_AGENT);
      float num   = __hip_atomic_load(scal + 1, __ATOMIC_RELAXED, __HIP_MEMORY_SCOPE_AGENT);
      float ortho = __hip_atomic_load(scal + 2, __ATOMIC_RELAXED, __HIP_MEMORY_SCOPE_AGENT);
      out[147456] = -num / den;
      out[147457] = ortho * (1.f / 64.f);
    }
  }
}

// -------------------- launch --------------------
extern "C" void kernel_launch(void* const* d_in, const int* in_sizes, int n_in,
                              void* d_out, int out_size, void* d_ws, size_t ws_size,
                              hipStream_t stream) {
  const float* x  = (const float*)d_in[0];
  const float* W  = (const float*)d_in[1];
  const float* bb = (const float*)d_in[2];
  const float* ew = (const float*)d_in[3];
  const int* esrc = (const int*)d_in[4];
  const int* edst = (const int*)d_in[5];
  float* out = (float*)d_out;
  float* ws = (float*)d_ws;

  float* s_buf   = ws;                                    // 1,638,400 f
  float* adj_raw = s_buf + (size_t)NN * KC;               // 16,384 f   <- zero region start
  float* cc_raw  = adj_raw + 16384;                       // 16,384 f
  float* outx    = cc_raw + 16384;                        // 131,072 f
  float* scal    = outx + 131072;                         // 8 f: [0]=den [1]=num [2]=ortho
  unsigned* done = (unsigned*)(scal + 8);                 // 8 u
  unsigned* deg  = done + 8;                              // 102,400 u (deg -> cursors -> row ends)
  unsigned* gtot = deg + NN;                              // 64 u       <- zero region end
  unsigned* gbase = gtot + BG;                            // 72 u (65 used)
  unsigned* pay  = gbase + 72;                            // NE u32 (dst_local<<16 | bf16 w), sorted by src
  // total ~= 20.8 MB (< 33.69 MB proven available)

  k_s<<<NN / 256, 256, 0, stream>>>(x, W, bb, s_buf, (unsigned*)adj_raw);
  k_hist<<<HB, 256, 0, stream>>>(esrc, deg, gtot);
  k_scan_b<<<1, 64, 0, stream>>>(gtot, gbase);
  k_scan_g<<<BG, 64, 0, stream>>>(deg, gbase);
  k_scatter<<<HB, 256, 0, stream>>>(ew, esrc, edst, deg, pay);
  k_adj<<<BG * 32, 256, 0, stream>>>(s_buf, pay, gbase, deg, adj_raw, scal);
  k_mid<<<BG * 16, 256, 0, stream>>>(s_buf, x, cc_raw, outx);
  k_post<<<64, 256, 0, stream>>>(adj_raw, cc_raw, outx, out, scal, done);
}

// Round 2
// 342.492 us; speedup vs baseline: 1.7419x; 1.7419x over previous
//
#include <hip/hip_runtime.h>
#include <math.h>

#define NN 102400
#define FD 128
#define KC 16
#define BG 64
#define NPG 1600
#define NE 3276800
#define HB 1024          // level-1 hist/scatter blocks
#define EH (NE / HB)     // 3200 edges per block
#define SMAX 56          // ceil(max edges-per-graph / 1024)
#define ZTOT (16384 + 16384 + 131072 + 8 + 8)   // u32s zeroed by k_s

__device__ __forceinline__ void glob_addf(float* p, float v) {
  unsafeAtomicAdd(p, v);
}
__device__ __forceinline__ unsigned f2bf(float f) {
  unsigned u = __float_as_uint(f);
  u += 0x7FFFu + ((u >> 16) & 1u);
  return (u >> 16) & 0xFFFFu;
}
__device__ __forceinline__ float bf2f(unsigned h) {
  return __uint_as_float(h << 16);
}

// -------------------- k_s: softmax^2(x@W+b) + zero accumulators --------------------
__global__ __launch_bounds__(256) void k_s(const float* __restrict__ x,
    const float* __restrict__ W, const float* __restrict__ bb,
    float* __restrict__ s, unsigned* __restrict__ zbase) {
  const int t = threadIdx.x;
  const int n = blockIdx.x * 256 + t;
  for (int i = n; i < ZTOT; i += NN) zbase[i] = 0u;
  float acc[KC];
#pragma unroll
  for (int k = 0; k < KC; ++k) acc[k] = bb[k];
  const float4* xr = (const float4*)(x + (size_t)n * FD);
#pragma unroll 4
  for (int c = 0; c < FD / 4; ++c) {
    float4 v = xr[c];
    const float* wr = W + c * 4 * KC;   // wave-uniform -> scalar loads
#pragma unroll
    for (int k = 0; k < KC; ++k)
      acc[k] += v.x * wr[k] + v.y * wr[KC + k] + v.z * wr[2 * KC + k] + v.w * wr[3 * KC + k];
  }
#pragma unroll
  for (int r = 0; r < 2; ++r) {
    float m = acc[0];
#pragma unroll
    for (int k = 1; k < KC; ++k) m = fmaxf(m, acc[k]);
    float sum = 0.f;
#pragma unroll
    for (int k = 0; k < KC; ++k) { acc[k] = expf(acc[k] - m); sum += acc[k]; }
    float inv = 1.f / sum;
#pragma unroll
    for (int k = 0; k < KC; ++k) acc[k] *= inv;
  }
  float4* so = (float4*)(s + (size_t)n * KC);
  so[0] = make_float4(acc[0], acc[1], acc[2], acc[3]);
  so[1] = make_float4(acc[4], acc[5], acc[6], acc[7]);
  so[2] = make_float4(acc[8], acc[9], acc[10], acc[11]);
  so[3] = make_float4(acc[12], acc[13], acc[14], acc[15]);
}

// -------------------- level-1: per-(graph,block) histogram --------------------
__global__ __launch_bounds__(256) void k_hist(const int* __restrict__ esrc,
    unsigned* __restrict__ blkhist) {
  __shared__ unsigned h[BG];
  const int t = threadIdx.x, b = blockIdx.x;
  if (t < BG) h[t] = 0u;
  __syncthreads();
  const int e0 = b * EH;
  for (int i = t; i < EH; i += 256) {
    unsigned g = (unsigned)esrc[e0 + i] / (unsigned)NPG;
    atomicAdd(&h[g], 1u);           // ds_add, no-return
  }
  __syncthreads();
  if (t < BG) blkhist[t * HB + b] = h[t];
}

// -------------------- level-1 scan A --------------------
__global__ __launch_bounds__(1024) void k_scan_a(unsigned* __restrict__ blkhist,
    unsigned* __restrict__ gtot) {
  __shared__ unsigned wsum[16];
  const int t = threadIdx.x, g = blockIdx.x;
  const int lane = t & 63;
  unsigned v = blkhist[g * HB + t];
  unsigned inc = v;
#pragma unroll
  for (int o = 1; o < 64; o <<= 1) {
    unsigned nb = __shfl_up(inc, o, 64);
    if (lane >= o) inc += nb;
  }
  if (lane == 63) wsum[t >> 6] = inc;
  __syncthreads();
  if (t == 0) {
    unsigned run = 0;
#pragma unroll
    for (int i = 0; i < 16; ++i) { unsigned c = wsum[i]; wsum[i] = run; run += c; }
    gtot[g] = run;
  }
  __syncthreads();
  blkhist[g * HB + t] = inc - v + wsum[t >> 6];
}

// -------------------- level-1 scan B --------------------
__global__ void k_scan_b(const unsigned* __restrict__ gtot, unsigned* __restrict__ gbase) {
  if (threadIdx.x == 0) {
    unsigned run = 0;
    for (int g = 0; g < BG; ++g) { gbase[g] = run; run += gtot[g]; }
    gbase[BG] = run;   // == NE
  }
}

// -------------------- level-1 scatter: sort by graph (write-local) --------------------
__global__ __launch_bounds__(256) void k_scatter1(const float* __restrict__ ew,
    const int* __restrict__ esrc, const int* __restrict__ edst,
    const unsigned* __restrict__ blkhist, const unsigned* __restrict__ gbase,
    unsigned short* __restrict__ skey, unsigned* __restrict__ pay) {
  __shared__ unsigned h[BG];
  __shared__ unsigned off[BG];
  const int t = threadIdx.x, b = blockIdx.x;
  if (t < BG) { h[t] = 0u; off[t] = gbase[t] + blkhist[t * HB + b]; }
  __syncthreads();
  const int e0 = b * EH;
  for (int i = t; i < EH; i += 256) {
    int e = e0 + i;
    int s0 = esrc[e], d0 = edst[e];
    float w = ew[e];
    unsigned g = (unsigned)s0 / (unsigned)NPG;
    unsigned r = atomicAdd(&h[g], 1u);
    unsigned pos = off[g] + r;
    skey[pos] = (unsigned short)((unsigned)s0 - g * NPG);
    pay[pos] = (((unsigned)d0 - g * NPG) << 16) | f2bf(w);
  }
}

// ------- level-2: per-graph in-place counting sort of PAYLOAD by src + row_ptr -------
// Register-snapshot pay, barrier, then scatter in place. Writes stay inside the
// graph's own ~200KB region -> L2-local, no partial-line HBM amplification.
__global__ __launch_bounds__(1024, 4) void k_sort2_pay(const unsigned short* __restrict__ skey,
    unsigned* __restrict__ pay, const unsigned* __restrict__ gbase,
    unsigned short* __restrict__ rowp) {
  __shared__ unsigned hist[NPG];
  __shared__ unsigned cur[NPG];
  const int t = threadIdx.x;
  const int g = blockIdx.x;
  const unsigned gb = gbase[g];
  const unsigned cnt = gbase[g + 1] - gb;   // ~51200, fits u16
  for (int i = t; i < NPG; i += 1024) hist[i] = 0u;
  __syncthreads();
  unsigned pv[SMAX];                        // register snapshot of payload
#pragma unroll
  for (int i = 0; i < SMAX; ++i) {
    unsigned e = (unsigned)t + (unsigned)(i * 1024);
    if (e < cnt) {
      pv[i] = pay[gb + e];
      atomicAdd(&hist[skey[gb + e]], 1u);
    }
  }
  __syncthreads();                          // all snapshot reads done before any write
  if (t < 64) {                             // wave-0 scan of 1600 counters
    unsigned loc[25];
    unsigned run = 0;
#pragma unroll
    for (int i = 0; i < 25; ++i) { loc[i] = run; run += hist[t * 25 + i]; }
    unsigned inc = run;
#pragma unroll
    for (int o = 1; o < 64; o <<= 1) {
      unsigned nb = __shfl_up(inc, o, 64);
      if (t >= o) inc += nb;
    }
    unsigned excl = inc - run;
#pragma unroll
    for (int i = 0; i < 25; ++i) cur[t * 25 + i] = excl + loc[i];
  }
  __syncthreads();
  for (int i = t; i < NPG; i += 1024) rowp[g * 1601 + i] = (unsigned short)cur[i];
  if (t == 0) rowp[g * 1601 + NPG] = (unsigned short)cnt;
  __syncthreads();
#pragma unroll
  for (int i = 0; i < SMAX; ++i) {          // in-place scatter of payload
    unsigned e = (unsigned)t + (unsigned)(i * 1024);
    if (e < cnt) {
      unsigned r = atomicAdd(&cur[skey[gb + e]], 1u);
      pay[gb + r] = pv[i];
    }
  }
}

// -------------------- k_adj: sequential payload, single dependent gather ----------
__global__ __launch_bounds__(256, 6) void k_adj(const float* __restrict__ s,
    const unsigned* __restrict__ pay, const unsigned* __restrict__ gbase,
    const unsigned short* __restrict__ rowp,
    float* __restrict__ adj_raw, float* __restrict__ den) {
  __shared__ float red[16 * 256];
  __shared__ float scr[4];
  const int t = threadIdx.x;
  const int g = blockIdx.x & 63;            // XCD-spread graphs
  const int oct = blockIdx.x >> 6;          // 0..31
  const int l = t & 15;
  const int slice = oct * 16 + (t >> 4);    // 0..511 per graph
  const int sw = (t >> 4) & 3;              // slice-in-wave
  const unsigned* pp = pay + gbase[g];
  const unsigned short* rp = rowp + g * 1601;
  const float* sG = s + (size_t)g * NPG * KC;
  float acc[16];
#pragma unroll
  for (int k = 0; k < 16; ++k) acc[k] = 0.f;
  float dacc = 0.f;
  for (int i = slice; i < NPG; i += 512) {
    const unsigned e0 = rp[i], e1 = rp[i + 1];
    float m = 0.f;
    unsigned e = e0;
    for (; e + 8 <= e1; e += 8) {           // 8 independent gathers in flight
      unsigned pk0 = pp[e],     pk1 = pp[e + 1], pk2 = pp[e + 2], pk3 = pp[e + 3];
      unsigned pk4 = pp[e + 4], pk5 = pp[e + 5], pk6 = pp[e + 6], pk7 = pp[e + 7];
      float sv0 = sG[(pk0 >> 16) * KC + l];
      float sv1 = sG[(pk1 >> 16) * KC + l];
      float sv2 = sG[(pk2 >> 16) * KC + l];
      float sv3 = sG[(pk3 >> 16) * KC + l];
      float sv4 = sG[(pk4 >> 16) * KC + l];
      float sv5 = sG[(pk5 >> 16) * KC + l];
      float sv6 = sG[(pk6 >> 16) * KC + l];
      float sv7 = sG[(pk7 >> 16) * KC + l];
      float t0 = bf2f(pk0 & 0xFFFFu) * sv0;
      float t1 = bf2f(pk1 & 0xFFFFu) * sv1;
      float t2 = bf2f(pk2 & 0xFFFFu) * sv2;
      float t3 = bf2f(pk3 & 0xFFFFu) * sv3;
      float t4 = bf2f(pk4 & 0xFFFFu) * sv4;
      float t5 = bf2f(pk5 & 0xFFFFu) * sv5;
      float t6 = bf2f(pk6 & 0xFFFFu) * sv6;
      float t7 = bf2f(pk7 & 0xFFFFu) * sv7;
      m += ((t0 + t1) + (t2 + t3)) + ((t4 + t5) + (t6 + t7));
      dacc = fmaf(t0, sv0, dacc);
      dacc = fmaf(t1, sv1, dacc);
      dacc = fmaf(t2, sv2, dacc);
      dacc = fmaf(t3, sv3, dacc);
      dacc = fmaf(t4, sv4, dacc);
      dacc = fmaf(t5, sv5, dacc);
      dacc = fmaf(t6, sv6, dacc);
      dacc = fmaf(t7, sv7, dacc);
    }
    for (; e < e1; ++e) {
      unsigned pk0 = pp[e];
      float sv0 = sG[(pk0 >> 16) * KC + l];
      float t0 = bf2f(pk0 & 0xFFFFu) * sv0;
      m += t0;
      dacc = fmaf(t0, sv0, dacc);
    }
    const float si = sG[i * KC + l];
#pragma unroll
    for (int k = 0; k < 16; ++k)
      acc[k] = fmaf(__shfl(si, sw * 16 + k, 64), m, acc[k]);
  }
  const int sb = t >> 4;
#pragma unroll
  for (int k = 0; k < 16; ++k) red[sb * 256 + k * 16 + l] = acc[k];
  __syncthreads();
  float sum = 0.f;
#pragma unroll
  for (int sl = 0; sl < 16; ++sl) sum += red[sl * 256 + t];
  glob_addf(adj_raw + g * 256 + t, sum);
#pragma unroll
  for (int o = 32; o > 0; o >>= 1) dacc += __shfl_down(dacc, o, 64);
  __syncthreads();
  if ((t & 63) == 0) scr[t >> 6] = dacc;
  __syncthreads();
  if (t == 0) glob_addf(den, scr[0] + scr[1] + scr[2] + scr[3]);
}

// -------------------- k_mid: CC = S^T S, out_x = S^T X -----------------------------
__global__ __launch_bounds__(256, 8) void k_mid(const float* __restrict__ s,
    const float* __restrict__ x, float* __restrict__ cc_raw,
    float* __restrict__ outx_raw) {
  __shared__ float st[100 * KC];
  const int t = threadIdx.x;
  const int g = blockIdx.x >> 4, sub = blockIdx.x & 15;
  const int n0 = g * NPG + sub * 100;
  const int j = t & 127, h = t >> 7;
  const int kc = t >> 4, lc = t & 15;
  for (int u = t; u < 100 * KC; u += 256) st[u] = s[(size_t)n0 * KC + u];
  __syncthreads();
  float accX[8] = {0.f, 0.f, 0.f, 0.f, 0.f, 0.f, 0.f, 0.f};
  float accC = 0.f;
  for (int i = 0; i < 100; ++i) {
    const float xv = x[(size_t)(n0 + i) * FD + j];
    const float* si = st + i * KC;
#pragma unroll
    for (int kk = 0; kk < 8; ++kk) accX[kk] = fmaf(si[h * 8 + kk], xv, accX[kk]);
    accC = fmaf(si[kc], si[lc], accC);
  }
#pragma unroll
  for (int kk = 0; kk < 8; ++kk)
    glob_addf(outx_raw + g * 2048 + (h * 8 + kk) * 128 + j, accX[kk]);
  glob_addf(cc_raw + g * 256 + t, accC);
}

// -------------------- k_post: normalize adj, trace, ortho, SELU --------------------
__device__ __forceinline__ float bred(float v, float* scr) {
#pragma unroll
  for (int o = 32; o > 0; o >>= 1) v += __shfl_down(v, o, 64);
  __syncthreads();
  if ((threadIdx.x & 63) == 0) scr[threadIdx.x >> 6] = v;
  __syncthreads();
  return scr[0] + scr[1] + scr[2] + scr[3];
}

__global__ __launch_bounds__(256) void k_post(const float* __restrict__ adj_raw,
    const float* __restrict__ cc_raw, const float* __restrict__ outx_raw,
    float* __restrict__ out, float* __restrict__ scal, unsigned* __restrict__ done) {
  const int b = blockIdx.x, t = threadIdx.x;
  const int k = t >> 4, l = t & 15;
  __shared__ float m[16 * 17];
  __shared__ float dk[16];
  __shared__ float scr[4];
  const float raw = adj_raw[b * 256 + t];
  const float masked = (k == l) ? 0.f : raw;
  m[k * 17 + l] = masked;
  __syncthreads();
  if (t < 16) {
    float rs = 0.f;
#pragma unroll
    for (int ll = 0; ll < 16; ++ll) rs += m[t * 17 + ll];
    dk[t] = sqrtf(rs) + 1e-12f;
  }
  __syncthreads();
  out[131072 + b * 256 + t] = masked / (dk[k] * dk[l]);
  float tr = bred((k == l) ? raw : 0.f, scr);
  if (t == 0) glob_addf(scal + 1, tr);
  const float c = cc_raw[b * 256 + t];
  float n2 = bred(c * c, scr);
  float diff = c / sqrtf(n2) - ((k == l) ? 0.25f : 0.f);
  float d2 = bred(diff * diff, scr);
  if (t == 0) glob_addf(scal + 2, sqrtf(d2));
  for (int idx = b * 256 + t; idx < 131072; idx += 16384) {
    float xv = outx_raw[idx];
    out[idx] = xv > 0.f ? 1.0507009873554805f * xv
                        : 1.0507009873554805f * 1.6732632423543772f * expm1f(xv);
  }
  __syncthreads();
  if (t == 0) {
    __threadfence();
    unsigned v = __hip_atomic_fetch_add(done, 1u, __ATOMIC_ACQ_REL,
                                        __HIP_MEMORY_SCOPE_AGENT);
    if (v == 63u) {   // last block: all contributions visible
      float den   = __hip_atomic_load(scal + 0, __ATOMIC_RELAXED, __HIP_MEMORY_SCOPE_AGENT);
      float num   = __hip_atomic_load(scal + 1, __ATOMIC_RELAXED, __HIP_MEMORY_SCOPE_AGENT);
      float ortho = __hip_atomic_load(scal + 2, __ATOMIC_RELAXED, __HIP_MEMORY_SCOPE_AGENT);
      out[147456] = -num / den;
      out[147457] = ortho * (1.f / 64.f);
    }
  }
}

// -------------------- launch --------------------
extern "C" void kernel_launch(void* const* d_in, const int* in_sizes, int n_in,
                              void* d_out, int out_size, void* d_ws, size_t ws_size,
                              hipStream_t stream) {
  const float* x  = (const float*)d_in[0];
  const float* W  = (const float*)d_in[1];
  const float* bb = (const float*)d_in[2];
  const float* ew = (const float*)d_in[3];
  const int* esrc = (const int*)d_in[4];
  const int* edst = (const int*)d_in[5];
  float* out = (float*)d_out;
  float* ws = (float*)d_ws;

  float* s_buf   = ws;                                    // 1,638,400 f
  float* adj_raw = s_buf + (size_t)NN * KC;               // 16,384 f   <- zero region start
  float* cc_raw  = adj_raw + 16384;                       // 16,384 f
  float* outx    = cc_raw + 16384;                        // 131,072 f
  float* scal    = outx + 131072;                         // 8 f: [0]=den [1]=num [2]=ortho
  unsigned* done = (unsigned*)(scal + 8);                 // 8 u        <- zero region end
  unsigned* blkhist = done + 8;                           // 64*1024 u
  unsigned* gtot    = blkhist + (size_t)BG * HB;          // 64 u
  unsigned* gbase   = gtot + BG;                          // 68 u (65 used)
  unsigned short* rowp = (unsigned short*)(gbase + 68);   // 64*1601 u16
  unsigned short* skey = rowp + 64 * 1601;                // NE u16 (src keys)
  unsigned* pay = (unsigned*)(skey + NE);                 // NE u32 (dst<<16 | bf16 w) -> sorted in place
  // total ~= 27.3 MB (< 33.69 MB proven available)

  k_s<<<NN / 256, 256, 0, stream>>>(x, W, bb, s_buf, (unsigned*)adj_raw);
  k_hist<<<HB, 256, 0, stream>>>(esrc, blkhist);
  k_scan_a<<<BG, 1024, 0, stream>>>(blkhist, gtot);
  k_scan_b<<<1, 64, 0, stream>>>(gtot, gbase);
  k_scatter1<<<HB, 256, 0, stream>>>(ew, esrc, edst, blkhist, gbase, skey, pay);
  k_sort2_pay<<<BG, 1024, 0, stream>>>(skey, pay, gbase, rowp);
  k_adj<<<BG * 32, 256, 0, stream>>>(s_buf, pay, gbase, rowp, adj_raw, scal);
  k_mid<<<BG * 16, 256, 0, stream>>>(s_buf, x, cc_raw, outx);
  k_post<<<64, 256, 0, stream>>>(adj_raw, cc_raw, outx, out, scal, done);
}